// Round 6
// baseline (126.633 us; speedup 1.0000x reference)
//
#include <hip/hip_runtime.h>

// x:  [N=4, C=256, H=56, W=56] fp32
// w1: [N, 1, 32, 9,  H, W]     (3x3, pad 1)
// w2: [N, 1, 32, 25, H, W]     (5x5, pad 2)
// out:[N, 2, 1, C, H, W]
// out[n,b,c,h,w] = sum_p wB[n, c%32, p, h, w] * x[n, c, h+dh, w+dw] (zero pad)
//
// R13 (resubmit — R5 bench died on container acquisition, no signal):
// R12 minus the LDS/barrier machinery:
//  - R12 post-mortem: depth-2 weight prefetch gained only ~1 us (29.3 us
//    kernel vs ~15-19 us HBM floor). Remaining gap = serial staging phase
//    (4 dependent global->LDS rounds + vmcnt(0) drain + barrier, all 16
//    waves/CU lockstepped) and the LDS round-trip for x that is L1/L2
//    resident anyway (16 KB/block).
//  - keep R8/R12 block mapping (1024 blocks, gsel pair at +-8 -> same XCD,
//    weights HBM-fetched once: R10 proved scattering c across XCDs costs
//    227 MB FETCH / 70 us).
//  - x read DIRECTLY per use: aligned float4 + 2 predicated float2 halos
//    per (di,g); zero-pad via predication. No __syncthreads anywhere ->
//    waves free-run, cold weight misses overlap across all waves.
//  - branches merged in one di loop: x window rows di=1..3 feed the 3x3
//    too; both weight streams in flight. w2 depth-2 row prefetch + all-9
//    early w1 loads kept from R12 (full unroll -> live set ~3 w2 rows).

#define N_  4
#define C_  256
#define H_  56
#define W_  56
#define HW_ 3136
#define WC_ 32

#define TILE 14

__global__ __launch_bounds__(256) void lconv_kernel(
    const float* __restrict__ x,
    const float* __restrict__ w1,
    const float* __restrict__ w2,
    float* __restrict__ out)
{
    const int b     = blockIdx.x;        // 0..1023
    const int tile  = b & 3;
    const int vlow  = (b >> 2) & 1;
    const int gsel  = (b >> 3) & 1;      // stride 8 -> gsel-pair on same XCD
    const int vhigh = (b >> 4) & 15;
    const int n     = b >> 8;
    const int v     = (vhigh << 1) | vlow;
    const int r0    = tile * TILE;
    const int nv    = n * WC_ + v;
    const int tid   = threadIdx.x;

    if (tid >= TILE * 14) return;        // 196 compute threads, no barriers

    const int row = tid / 14;            // 0..13
    const int s   = tid - row * 14;
    const int wb  = 4 * s;               // 0,4,...,52
    const int h   = r0 + row;
    const int hw  = h * W_ + wb;

    const float* w1t = w1 + (size_t)nv * 9  * HW_ + hw;
    const float* w2t = w2 + (size_t)nv * 25 * HW_ + hw;
    const int c0 = gsel * 128 + v;
    const float* xb = x + (size_t)(n * C_ + c0) * HW_ + wb;   // plane g: +g*32*HW_

    float a2[4][4], a1[4][4];
    #pragma unroll
    for (int g = 0; g < 4; ++g)
        #pragma unroll
        for (int p = 0; p < 4; ++p) { a2[g][p] = 0.f; a1[g][p] = 0.f; }

    // ---- weight pipeline: w2 rows 0,1 + all 9 w1 float4 issued up front ----
    float4 w2r[5][5];                    // [di][dj], fully static-indexed
    #pragma unroll
    for (int dj = 0; dj < 5; ++dj)
        w2r[0][dj] = *(const float4*)(w2t + (size_t)dj * HW_);
    #pragma unroll
    for (int dj = 0; dj < 5; ++dj)
        w2r[1][dj] = *(const float4*)(w2t + (size_t)(5 + dj) * HW_);

    float4 w1r[9];
    #pragma unroll
    for (int q = 0; q < 9; ++q)
        w1r[q] = *(const float4*)(w1t + (size_t)q * HW_);

    const bool okL = (s > 0);            // left halo cols wb-2,wb-1 valid
    const bool okR = (s < 13);           // right halo cols wb+4,wb+5 valid

    #pragma unroll
    for (int di = 0; di < 5; ++di) {
        if (di + 2 < 5) {                // w2 row di+2, used 2 iters later
            #pragma unroll
            for (int dj = 0; dj < 5; ++dj)
                w2r[di + 2][dj] = *(const float4*)(w2t + (size_t)((di + 2) * 5 + dj) * HW_);
        }
        const int xr    = h - 2 + di;
        const bool rok  = (xr >= 0) && (xr < H_);
        const bool do33 = (di >= 1) && (di <= 3);

        #pragma unroll
        for (int g = 0; g < 4; ++g) {
            // x window cols wb-2 .. wb+5 of row xr (zero padded)
            const float* xp = xb + (size_t)g * WC_ * HW_ + xr * W_;
            float4 xm = make_float4(0.f, 0.f, 0.f, 0.f);
            float2 xl = make_float2(0.f, 0.f);
            float2 xh = make_float2(0.f, 0.f);
            if (rok) {
                xm = *(const float4*)(xp);
                if (okL) xl = *(const float2*)(xp - 2);
                if (okR) xh = *(const float2*)(xp + 4);
            }
            const float xw[8] = {xl.x, xl.y, xm.x, xm.y, xm.z, xm.w, xh.x, xh.y};

            #pragma unroll
            for (int dj = 0; dj < 5; ++dj) {
                const float* wr = (const float*)&w2r[di][dj];
                #pragma unroll
                for (int p = 0; p < 4; ++p)
                    a2[g][p] += wr[p] * xw[p + dj];      // out col wb+p
            }
            if (do33) {
                #pragma unroll
                for (int dj = 0; dj < 3; ++dj) {
                    const float* wr = (const float*)&w1r[(di - 1) * 3 + dj];
                    #pragma unroll
                    for (int p = 0; p < 4; ++p)
                        a1[g][p] += wr[p] * xw[p + dj + 1];
                }
            }
        }
    }

    #pragma unroll
    for (int g = 0; g < 4; ++g) {
        const int ch = c0 + g * WC_;
        float* o2 = out + ((size_t)(n * 2 + 1) * C_ + ch) * HW_ + hw;
        float* o1 = out + ((size_t)(n * 2 + 0) * C_ + ch) * HW_ + hw;
        *(float4*)(o2) = make_float4(a2[g][0], a2[g][1], a2[g][2], a2[g][3]);
        *(float4*)(o1) = make_float4(a1[g][0], a1[g][1], a1[g][2], a1[g][3]);
    }
}

extern "C" void kernel_launch(void* const* d_in, const int* in_sizes, int n_in,
                              void* d_out, int out_size, void* d_ws, size_t ws_size,
                              hipStream_t stream) {
    const float* x  = (const float*)d_in[0];
    const float* w1 = (const float*)d_in[1];
    const float* w2 = (const float*)d_in[2];
    float* out = (float*)d_out;

    dim3 grid(1024), block(256);   // 4 blocks/CU
    hipLaunchKernelGGL(lconv_kernel, grid, block, 0, stream, x, w1, w2, out);
}

// Round 8
// 112.330 us; speedup vs baseline: 1.1273x; 1.1273x over previous
//
#include <hip/hip_runtime.h>

// x:  [N=4, C=256, H=56, W=56] fp32
// w1: [N, 1, 32, 9,  H, W]     (3x3, pad 1)
// w2: [N, 1, 32, 25, H, W]     (5x5, pad 2)
// out:[N, 2, 1, C, H, W]
// out[n,b,c,h,w] = sum_p wB[n, c%32, p, h, w] * x[n, c, h+dh, w+dw] (zero pad)
//
// R15 = R14 with the compile fix: __builtin_nontemporal_store needs a NATIVE
// vector type, not HIP_vector_type<float,4>. Use ext_vector_type(4) float
// (layout-identical to float4) -> emits global_store_dwordx4 ... nt.
// Theory unchanged from R14:
//  - R13 counters: FETCH 35 MB + WRITE 25 MB = ~60 MB L2-miss traffic at
//    ~29 us -> latency/L2-bound, not HBM-BW-bound.
//  - Output (25.7 MB) is written once, never read. L2 write-allocate would
//    both add hidden RFO fetch and evict the weight stream from L2, which
//    the gsel-pair weight dedup depends on (R10: breaking dedup = 227 MB
//    FETCH / 70 us). NT stores keep L2 for weights.
// Everything else identical to R12: TILE 14, gsel split, LSTRIDE 68,
// 196 compute threads, w2 depth-2 row prefetch, all-9 early w1 loads.

#define N_  4
#define C_  256
#define H_  56
#define W_  56
#define HW_ 3136
#define WC_ 32

#define TILE    14
#define LROWS   18   // TILE + 4 halo rows
#define LSTRIDE 68   // x col c -> slot c+2; slots 0,1 & 58,59 zero halo

typedef float vfloat4 __attribute__((ext_vector_type(4)));

__global__ __launch_bounds__(256) void lconv_kernel(
    const float* __restrict__ x,
    const float* __restrict__ w1,
    const float* __restrict__ w2,
    float* __restrict__ out)
{
    __shared__ float lds[4 * LROWS * LSTRIDE];   // 19584 B

    const int b     = blockIdx.x;        // 0..1023
    const int tile  = b & 3;
    const int vlow  = (b >> 2) & 1;
    const int gsel  = (b >> 3) & 1;      // stride 8 -> gsel-pair on same XCD
    const int vhigh = (b >> 4) & 15;
    const int n     = b >> 8;
    const int v     = (vhigh << 1) | vlow;
    const int r0    = tile * TILE;
    const int nv    = n * WC_ + v;
    const int tid   = threadIdx.x;

    // ---- stage x: 4 planes x 18 rows x 56 cols; zero OOB rows ----
    for (int idx = tid; idx < 4 * LROWS * 14; idx += 256) {
        const int c4 = idx % 14;
        const int t2 = idx / 14;
        const int lr = t2 % LROWS;
        const int pl = t2 / LROWS;
        const int gr = r0 - 2 + lr;
        float4 val = make_float4(0.f, 0.f, 0.f, 0.f);
        if (gr >= 0 && gr < H_) {
            const int ch = gsel * 128 + pl * 32 + v;
            val = *(const float4*)(x + (size_t)(n * C_ + ch) * HW_ + gr * W_ + c4 * 4);
        }
        float* lp = &lds[(pl * LROWS + lr) * LSTRIDE + 4 * c4 + 2];
        *(float2*)(lp)     = make_float2(val.x, val.y);
        *(float2*)(lp + 2) = make_float2(val.z, val.w);
    }
    // zero column halos: slots 0,1 (x cols -2,-1) and 58,59 (x cols 56,57)
    for (int idx = tid; idx < 4 * LROWS * 4; idx += 256) {
        const int k  = idx & 3;
        const int t2 = idx >> 2;
        const int lr = t2 % LROWS;
        const int pl = t2 / LROWS;
        const int slot = (k < 2) ? k : (56 + k);
        lds[(pl * LROWS + lr) * LSTRIDE + slot] = 0.f;
    }
    __syncthreads();

    if (tid >= TILE * 14) return;        // 196 compute threads; no barriers below

    const int row = tid / 14;            // 0..13
    const int s   = tid - row * 14;
    const int wb  = 4 * s;               // 0,4,...,52
    const int h   = r0 + row;
    const int hw  = h * W_ + wb;

    const float* w1t = w1 + (size_t)nv * 9  * HW_ + hw;
    const float* w2t = w2 + (size_t)nv * 25 * HW_ + hw;
    const int c0 = gsel * 128 + v;

    // ================= 5x5 branch: depth-2 row pipeline, full unroll ======
    float a2[4][4];
    #pragma unroll
    for (int g = 0; g < 4; ++g)
        #pragma unroll
        for (int p = 0; p < 4; ++p) a2[g][p] = 0.f;

    float4 w2r[5][5];                    // [di][dj], fully static-indexed
    #pragma unroll
    for (int dj = 0; dj < 5; ++dj)
        w2r[0][dj] = *(const float4*)(w2t + (size_t)dj * HW_);
    #pragma unroll
    for (int dj = 0; dj < 5; ++dj)
        w2r[1][dj] = *(const float4*)(w2t + (size_t)(5 + dj) * HW_);

    // w1 loads issued here: they complete during the whole 5x5 phase
    float4 w1r[9];
    #pragma unroll
    for (int q = 0; q < 9; ++q)
        w1r[q] = *(const float4*)(w1t + (size_t)q * HW_);

    #pragma unroll
    for (int di = 0; di < 5; ++di) {
        if (di + 2 < 5) {                // prefetch row di+2, used 2 iters later
            #pragma unroll
            for (int dj = 0; dj < 5; ++dj)
                w2r[di + 2][dj] = *(const float4*)(w2t + (size_t)((di + 2) * 5 + dj) * HW_);
        }
        #pragma unroll
        for (int g = 0; g < 4; ++g) {
            const float* lp = &lds[(g * LROWS + row + di) * LSTRIDE + wb];
            const float4 xa  = *(const float4*)(lp);
            const float4 xb4 = *(const float4*)(lp + 4);
            const float xw[8] = {xa.x, xa.y, xa.z, xa.w, xb4.x, xb4.y, xb4.z, xb4.w};
            #pragma unroll
            for (int dj = 0; dj < 5; ++dj) {
                const float* wr = (const float*)&w2r[di][dj];
                #pragma unroll
                for (int p = 0; p < 4; ++p)
                    a2[g][p] += wr[p] * xw[p + dj];
            }
        }
    }

    float* o2 = out + ((size_t)(n * 2 + 1) * C_ + c0) * HW_ + hw;
    #pragma unroll
    for (int g = 0; g < 4; ++g) {
        vfloat4 sv = {a2[g][0], a2[g][1], a2[g][2], a2[g][3]};
        __builtin_nontemporal_store(sv, (vfloat4*)(o2 + (size_t)g * WC_ * HW_));
    }

    // ================= 3x3 branch: weights already in registers ===========
    float a1[4][4];
    #pragma unroll
    for (int g = 0; g < 4; ++g)
        #pragma unroll
        for (int p = 0; p < 4; ++p) a1[g][p] = 0.f;

    #pragma unroll
    for (int di = 0; di < 3; ++di) {
        #pragma unroll
        for (int g = 0; g < 4; ++g) {
            // x rows h-1+di -> LDS row row+1+di
            const float* lp = &lds[(g * LROWS + row + 1 + di) * LSTRIDE + wb];
            const float4 xa  = *(const float4*)(lp);
            const float4 xb4 = *(const float4*)(lp + 4);
            const float xw[8] = {xa.x, xa.y, xa.z, xa.w, xb4.x, xb4.y, xb4.z, xb4.w};
            #pragma unroll
            for (int dj = 0; dj < 3; ++dj) {
                const float* wr = (const float*)&w1r[di * 3 + dj];
                #pragma unroll
                for (int p = 0; p < 4; ++p)
                    a1[g][p] += wr[p] * xw[p + dj + 1];
            }
        }
    }

    float* o1 = out + ((size_t)(n * 2 + 0) * C_ + c0) * HW_ + hw;
    #pragma unroll
    for (int g = 0; g < 4; ++g) {
        vfloat4 sv = {a1[g][0], a1[g][1], a1[g][2], a1[g][3]};
        __builtin_nontemporal_store(sv, (vfloat4*)(o1 + (size_t)g * WC_ * HW_));
    }
}

extern "C" void kernel_launch(void* const* d_in, const int* in_sizes, int n_in,
                              void* d_out, int out_size, void* d_ws, size_t ws_size,
                              hipStream_t stream) {
    const float* x  = (const float*)d_in[0];
    const float* w1 = (const float*)d_in[1];
    const float* w2 = (const float*)d_in[2];
    float* out = (float*)d_out;

    dim3 grid(1024), block(256);   // 4 blocks/CU
    hipLaunchKernelGGL(lconv_kernel, grid, block, 0, stream, x, w1, w2, out);
}